// Round 1
// baseline (227.314 us; speedup 1.0000x reference)
//
#include <hip/hip_runtime.h>
#include <hip/hip_bf16.h>
#include <stdint.h>

typedef unsigned short u16;
typedef __attribute__((ext_vector_type(8))) short short8;
typedef __attribute__((ext_vector_type(4))) float float4v;

#define CH 128
#define OO 128
#define KD 1152      // 9*128
#define MPIX 32768   // 8*64*64

__device__ __forceinline__ u16 f2bf(float v) {
    __hip_bfloat16 h = __float2bfloat16(v);
    return *reinterpret_cast<u16*>(&h);
}

// ---------------- transpose x (B,C,H,W) f32 -> xt (B,H,W,C) bf16 ----------------
__global__ __launch_bounds__(256) void transpose_kernel(const float* __restrict__ x,
                                                        __hip_bfloat16* __restrict__ xt) {
    __shared__ float st[64][65];
    int tid = threadIdx.x;
    int bh = blockIdx.x;              // b*64 + h
    int b = bh >> 6;
    int h = bh & 63;
    const float* xb = x + ((size_t)b * CH) * 4096 + (size_t)h * 64;
    __hip_bfloat16* xo = xt + ((size_t)bh << 6) * CH;   // ((b*64+h)*64)*128
    for (int cc0 = 0; cc0 < 128; cc0 += 64) {
        #pragma unroll
        for (int step = 0; step < 16; ++step) {
            int cl = (tid >> 6) + step * 4;
            int w = tid & 63;
            st[cl][w] = xb[(size_t)(cc0 + cl) * 4096 + w];
        }
        __syncthreads();
        #pragma unroll
        for (int step = 0; step < 16; ++step) {
            int w = (tid >> 6) + step * 4;
            int cl = tid & 63;
            xo[(size_t)w * CH + cc0 + cl] = __float2bfloat16(st[cl][w]);
        }
        __syncthreads();
    }
}

// ---------------- offset conv: only the 6 needed channels, 4-way c-split ----------------
// channels: s=0..2 -> x-comp ch {0,6,12}; s=3..5 -> y-comp ch {1,3,5}
__global__ __launch_bounds__(256) void offset_conv_kernel(const float* __restrict__ x,
                                                          const float* __restrict__ w_off,
                                                          float* __restrict__ partial) {
    int tid = threadIdx.x;
    int m = blockIdx.x * 256 + tid;
    int chunk = blockIdx.y;           // 0..3, 32 channels each
    int b = m >> 12;
    int hw = m & 4095;
    int h = hw >> 6;
    int w = hw & 63;
    float acc[6] = {0.f, 0.f, 0.f, 0.f, 0.f, 0.f};
    int c0 = chunk * 32;
    for (int c = c0; c < c0 + 32; ++c) {
        const float* xc = x + ((size_t)(b * CH + c) << 12);
        float xv[9];
        #pragma unroll
        for (int dy = 0; dy < 3; ++dy) {
            int yy = h + dy - 1;
            bool vy = (unsigned)yy < 64u;
            #pragma unroll
            for (int dx = 0; dx < 3; ++dx) {
                int xx = w + dx - 1;
                bool vv = vy && ((unsigned)xx < 64u);
                xv[dy * 3 + dx] = vv ? xc[yy * 64 + xx] : 0.f;
            }
        }
        const float* wb = w_off + (size_t)c * 9;
        #pragma unroll
        for (int s = 0; s < 6; ++s) {
            int chn = (s < 3) ? s * 6 : (s - 3) * 2 + 1;
            const float* wp = wb + (size_t)chn * (CH * 9);
            float a = acc[s];
            #pragma unroll
            for (int t = 0; t < 9; ++t) a = fmaf(xv[t], wp[t], a);
            acc[s] = a;
        }
    }
    float* po = partial + ((size_t)(chunk << 15) + m) * 6;
    #pragma unroll
    for (int s = 0; s < 6; ++s) po[s] = acc[s];
}

// ---------------- reorder w_main (O,C,3,3) f32 -> Wb[o][k*128+c] bf16 ----------------
__global__ __launch_bounds__(256) void wreorder_kernel(const float* __restrict__ w_main,
                                                       u16* __restrict__ Wb) {
    int idx = blockIdx.x * 256 + threadIdx.x;
    if (idx >= OO * KD) return;
    int o = idx / KD;
    int r = idx - o * KD;
    int k = r >> 7;
    int c = r & 127;
    Wb[idx] = f2bf(w_main[(size_t)o * KD + c * 9 + k]);
}

// ---------------- deformable im2col: Apix[m][k*128+c] bf16 ----------------
__global__ __launch_bounds__(256) void im2col_kernel(const __hip_bfloat16* __restrict__ xt,
                                                     const float* __restrict__ partial,
                                                     const float* __restrict__ b_off,
                                                     u16* __restrict__ Apix) {
    int tid = threadIdx.x;
    int m = blockIdx.x;
    int c = tid & 127;
    int khalf = tid >> 7;             // wave-uniform
    int b = m >> 12;
    int hw = m & 4095;
    int h = hw >> 6;
    int w = hw & 63;

    float o6[6];
    #pragma unroll
    for (int s = 0; s < 6; ++s) {
        int chn = (s < 3) ? s * 6 : (s - 3) * 2 + 1;
        float v = b_off[chn];
        #pragma unroll
        for (int q = 0; q < 4; ++q) v += partial[((size_t)(q << 15) + m) * 6 + s];
        o6[s] = v;
    }
    float oxs[3], oys[3];
    oxs[0] = o6[0]; oxs[1] = oxs[0] + o6[1]; oxs[2] = oxs[1] + o6[2];
    oys[0] = o6[3]; oys[1] = oys[0] + o6[4]; oys[2] = oys[1] + o6[5];

    const float step = 2.0f / 63.0f;
    float bxn = -1.0f + w * step;
    float byn = -1.0f + h * step;
    const __hip_bfloat16* xb = xt + (((size_t)b << 12) * CH);
    u16* ao = Apix + (size_t)m * KD;

    for (int k = khalf; k < 9; k += 2) {
        int i = k / 3;
        int j = k - i * 3;
        float gx = fmaf(bxn + oxs[i], 32.0f, 31.5f);   // (gxn+1)*32 - 0.5
        float gy = fmaf(byn + oys[j], 32.0f, 31.5f);
        float x0f = floorf(gx), y0f = floorf(gy);
        float wx = gx - x0f, wy = gy - y0f;
        int ix0 = (int)x0f, iy0 = (int)y0f;
        int ix1 = ix0 + 1, iy1 = iy0 + 1;
        bool vx0 = (unsigned)ix0 < 64u, vx1 = (unsigned)ix1 < 64u;
        bool vy0 = (unsigned)iy0 < 64u, vy1 = (unsigned)iy1 < 64u;
        float v00 = 0.f, v01 = 0.f, v10 = 0.f, v11 = 0.f;
        if (vy0 && vx0) v00 = __bfloat162float(xb[(size_t)(iy0 * 64 + ix0) * CH + c]);
        if (vy0 && vx1) v01 = __bfloat162float(xb[(size_t)(iy0 * 64 + ix1) * CH + c]);
        if (vy1 && vx0) v10 = __bfloat162float(xb[(size_t)(iy1 * 64 + ix0) * CH + c]);
        if (vy1 && vx1) v11 = __bfloat162float(xb[(size_t)(iy1 * 64 + ix1) * CH + c]);
        float val = (1.f - wy) * ((1.f - wx) * v00 + wx * v01)
                  + wy * ((1.f - wx) * v10 + wx * v11);
        ao[k * 128 + c] = f2bf(val);
    }
}

// ---------------- GEMM: out[b,o,h,w] = sum_kc Wb[o,kc]*Apix[m,kc] + b_main[o] ----------------
// MFMA M dim = o (128 = whole O), N dim = pixel tile (128), K = 1152, BK=32
__global__ __launch_bounds__(256) void gemm_kernel(const u16* __restrict__ Wb,
                                                   const u16* __restrict__ Apix,
                                                   const float* __restrict__ b_main,
                                                   float* __restrict__ out) {
    __shared__ __align__(16) u16 lA[128 * 32];
    __shared__ __align__(16) u16 lB[128 * 32];
    int tid = threadIdx.x;
    int wave = tid >> 6;
    int lane = tid & 63;
    int wm = wave & 1;                // o half
    int wn = wave >> 1;               // pixel half
    int pb = blockIdx.x * 128;        // pixel tile base
    int mrow = lane & 15;
    int q8 = (lane >> 4) * 8;

    float4v acc[4][4];
    #pragma unroll
    for (int sm = 0; sm < 4; ++sm)
        #pragma unroll
        for (int sn = 0; sn < 4; ++sn)
            acc[sm][sn] = (float4v){0.f, 0.f, 0.f, 0.f};

    const u16* Bp = Apix + (size_t)pb * KD;

    for (int kk = 0; kk < 36; ++kk) {
        int col0 = kk * 32;
        #pragma unroll
        for (int q = 0; q < 2; ++q) {
            int idx = q * 256 + tid;
            int row = idx >> 2;
            int cole = (idx & 3) * 8;
            *(uint4*)&lA[idx * 8] = *(const uint4*)(Wb + (size_t)row * KD + col0 + cole);
            *(uint4*)&lB[idx * 8] = *(const uint4*)(Bp + (size_t)row * KD + col0 + cole);
        }
        __syncthreads();
        short8 af[4], bfv[4];
        #pragma unroll
        for (int s = 0; s < 4; ++s) {
            af[s]  = *(const short8*)&lA[(wm * 64 + s * 16 + mrow) * 32 + q8];
            bfv[s] = *(const short8*)&lB[(wn * 64 + s * 16 + mrow) * 32 + q8];
        }
        #pragma unroll
        for (int sm = 0; sm < 4; ++sm)
            #pragma unroll
            for (int sn = 0; sn < 4; ++sn)
                acc[sm][sn] = __builtin_amdgcn_mfma_f32_16x16x32_bf16(af[sm], bfv[sn],
                                                                     acc[sm][sn], 0, 0, 0);
        __syncthreads();
    }

    // epilogue: C/D layout col=lane&15 (pixel), row=(lane>>4)*4+r (o)
    #pragma unroll
    for (int sm = 0; sm < 4; ++sm) {
        int o = wm * 64 + sm * 16 + (lane >> 4) * 4;
        #pragma unroll
        for (int sn = 0; sn < 4; ++sn) {
            int pcol = pb + wn * 64 + sn * 16 + mrow;
            int b = pcol >> 12;
            int rem = pcol & 4095;
            float* op = out + (((size_t)b * OO) << 12) + rem;
            #pragma unroll
            for (int r = 0; r < 4; ++r)
                op[(size_t)(o + r) << 12] = acc[sm][sn][r] + b_main[o + r];
        }
    }
}

extern "C" void kernel_launch(void* const* d_in, const int* in_sizes, int n_in,
                              void* d_out, int out_size, void* d_ws, size_t ws_size,
                              hipStream_t stream) {
    const float* x      = (const float*)d_in[0];
    const float* w_off  = (const float*)d_in[1];
    const float* b_off  = (const float*)d_in[2];
    const float* w_main = (const float*)d_in[3];
    const float* b_main = (const float*)d_in[4];
    float* out = (float*)d_out;

    char* ws = (char*)d_ws;
    __hip_bfloat16* xt = (__hip_bfloat16*)ws;                         // 8 MB
    float* partial = (float*)(ws + 8388608);                          // 3 MB (4 chunks x 32768 x 6)
    u16* Wb   = (u16*)(ws + 8388608 + 3145728);                       // 288 KB
    u16* Apix = (u16*)(ws + 8388608 + 3145728 + 294912);              // 72 MB

    transpose_kernel<<<512, 256, 0, stream>>>(x, xt);
    offset_conv_kernel<<<dim3(128, 4), 256, 0, stream>>>(x, w_off, partial);
    wreorder_kernel<<<576, 256, 0, stream>>>(w_main, Wb);
    im2col_kernel<<<32768, 256, 0, stream>>>(xt, partial, b_off, Apix);
    gemm_kernel<<<256, 256, 0, stream>>>(Wb, Apix, b_main, out);
}

// Round 2
// 140.877 us; speedup vs baseline: 1.6136x; 1.6136x over previous
//
#include <hip/hip_runtime.h>
#include <hip/hip_bf16.h>
#include <stdint.h>

typedef unsigned short u16;
typedef unsigned int u32;
typedef __attribute__((ext_vector_type(8))) short short8;
typedef __attribute__((ext_vector_type(4))) float float4v;

#define CH 128
#define OO 128
#define KD 1152      // 9*128
#define MPIX 32768   // 8*64*64
#define IMB 16       // pixels per im2col block

__device__ __forceinline__ u16 f2bf(float v) {
    __hip_bfloat16 h = __float2bfloat16(v);
    return *reinterpret_cast<u16*>(&h);
}

__device__ __forceinline__ float bf_lo(u32 u) {      // low bf16 of pair -> f32 (exact)
    u32 t = u << 16;
    return __builtin_bit_cast(float, t);
}
__device__ __forceinline__ float bf_hi(u32 u) {      // high bf16 of pair -> f32 (exact)
    u32 t = u & 0xffff0000u;
    return __builtin_bit_cast(float, t);
}
__device__ __forceinline__ u32 pack_bf16(float lo, float hi) {  // round-to-nearest (ties away)
    u32 ul = __builtin_bit_cast(u32, lo);
    u32 uh = __builtin_bit_cast(u32, hi);
    return ((ul + 0x8000u) >> 16) | ((uh + 0x8000u) & 0xffff0000u);
}

// ---------------- transpose x (B,C,H,W) f32 -> xt (B,H,W,C) bf16 ----------------
__global__ __launch_bounds__(256) void transpose_kernel(const float* __restrict__ x,
                                                        __hip_bfloat16* __restrict__ xt) {
    __shared__ float st[64][65];
    int tid = threadIdx.x;
    int bh = blockIdx.x;              // b*64 + h
    int b = bh >> 6;
    int h = bh & 63;
    const float* xb = x + ((size_t)b * CH) * 4096 + (size_t)h * 64;
    __hip_bfloat16* xo = xt + ((size_t)bh << 6) * CH;
    for (int cc0 = 0; cc0 < 128; cc0 += 64) {
        #pragma unroll
        for (int step = 0; step < 16; ++step) {
            int cl = (tid >> 6) + step * 4;
            int w = tid & 63;
            st[cl][w] = xb[(size_t)(cc0 + cl) * 4096 + w];
        }
        __syncthreads();
        #pragma unroll
        for (int step = 0; step < 16; ++step) {
            int w = (tid >> 6) + step * 4;
            int cl = tid & 63;
            xo[(size_t)w * CH + cc0 + cl] = __float2bfloat16(st[cl][w]);
        }
        __syncthreads();
    }
}

// ---------------- offset conv: only the 6 needed channels, 4-way c-split ----------------
__global__ __launch_bounds__(256) void offset_conv_kernel(const float* __restrict__ x,
                                                          const float* __restrict__ w_off,
                                                          float* __restrict__ partial) {
    int tid = threadIdx.x;
    int m = blockIdx.x * 256 + tid;
    int chunk = blockIdx.y;           // 0..3, 32 channels each
    int b = m >> 12;
    int hw = m & 4095;
    int h = hw >> 6;
    int w = hw & 63;
    float acc[6] = {0.f, 0.f, 0.f, 0.f, 0.f, 0.f};
    int c0 = chunk * 32;
    for (int c = c0; c < c0 + 32; ++c) {
        const float* xc = x + ((size_t)(b * CH + c) << 12);
        float xv[9];
        #pragma unroll
        for (int dy = 0; dy < 3; ++dy) {
            int yy = h + dy - 1;
            bool vy = (unsigned)yy < 64u;
            #pragma unroll
            for (int dx = 0; dx < 3; ++dx) {
                int xx = w + dx - 1;
                bool vv = vy && ((unsigned)xx < 64u);
                xv[dy * 3 + dx] = vv ? xc[yy * 64 + xx] : 0.f;
            }
        }
        const float* wb = w_off + (size_t)c * 9;
        #pragma unroll
        for (int s = 0; s < 6; ++s) {
            int chn = (s < 3) ? s * 6 : (s - 3) * 2 + 1;
            const float* wp = wb + (size_t)chn * (CH * 9);
            float a = acc[s];
            #pragma unroll
            for (int t = 0; t < 9; ++t) a = fmaf(xv[t], wp[t], a);
            acc[s] = a;
        }
    }
    float* po = partial + ((size_t)(chunk << 15) + m) * 6;
    #pragma unroll
    for (int s = 0; s < 6; ++s) po[s] = acc[s];
}

// ---------------- reorder w_main (O,C,3,3) f32 -> Wb[o][k*128+c] bf16 ----------------
__global__ __launch_bounds__(256) void wreorder_kernel(const float* __restrict__ w_main,
                                                       u16* __restrict__ Wb) {
    int idx = blockIdx.x * 256 + threadIdx.x;
    if (idx >= OO * KD) return;
    int o = idx / KD;
    int r = idx - o * KD;
    int k = r >> 7;
    int c = r & 127;
    Wb[idx] = f2bf(w_main[(size_t)o * KD + c * 9 + k]);
}

// ---------------- deformable im2col v2: 8 channels/thread, 16 pixels/block ----------------
__global__ __launch_bounds__(256) void im2col_kernel(const __hip_bfloat16* __restrict__ xt,
                                                     const float* __restrict__ partial,
                                                     const float* __restrict__ b_off,
                                                     u16* __restrict__ Apix) {
    __shared__ float offs[IMB][6];
    __shared__ float2 gxy[IMB][9];
    int tid = threadIdx.x;
    int m0 = blockIdx.x * IMB;
    int b = m0 >> 12;
    int h = (m0 & 4095) >> 6;
    int w0 = m0 & 63;                 // pixels m0..m0+15 share b and h

    if (tid < IMB * 6) {
        int pix = tid / 6, s = tid % 6;
        int m = m0 + pix;
        int chn = (s < 3) ? s * 6 : (s - 3) * 2 + 1;
        float v = b_off[chn];
        #pragma unroll
        for (int q = 0; q < 4; ++q) v += partial[((size_t)(q << 15) + m) * 6 + s];
        offs[pix][s] = v;
    }
    __syncthreads();
    if (tid < IMB * 9) {
        int pix = tid / 9, k = tid % 9;
        int i = k / 3, j = k - i * 3;
        float ox = offs[pix][0];
        if (i >= 1) ox += offs[pix][1];
        if (i >= 2) ox += offs[pix][2];
        float oy = offs[pix][3];
        if (j >= 1) oy += offs[pix][4];
        if (j >= 2) oy += offs[pix][5];
        const float step = 2.0f / 63.0f;
        float bxn = -1.0f + (w0 + pix) * step;
        float byn = -1.0f + h * step;
        gxy[pix][k] = make_float2(fmaf(bxn + ox, 32.0f, 31.5f),
                                  fmaf(byn + oy, 32.0f, 31.5f));
    }
    __syncthreads();

    int pix = tid >> 4;               // 0..15
    int c8 = (tid & 15) * 8;          // channel group base
    const u32* xb = (const u32*)(xt + (((size_t)b << 12) * CH));  // pairs of bf16
    u16* ao = Apix + (size_t)(m0 + pix) * KD + c8;

    for (int k = 0; k < 9; ++k) {
        float2 g = gxy[pix][k];
        float x0f = floorf(g.x), y0f = floorf(g.y);
        float wx = g.x - x0f, wy = g.y - y0f;
        int ix0 = (int)x0f, iy0 = (int)y0f;
        int ix1 = ix0 + 1, iy1 = iy0 + 1;
        float fx0 = ((unsigned)ix0 < 64u) ? 1.f : 0.f;
        float fx1 = ((unsigned)ix1 < 64u) ? 1.f : 0.f;
        float fy0 = ((unsigned)iy0 < 64u) ? 1.f : 0.f;
        float fy1 = ((unsigned)iy1 < 64u) ? 1.f : 0.f;
        float w00 = (1.f - wy) * (1.f - wx) * fy0 * fx0;
        float w01 = (1.f - wy) * wx * fy0 * fx1;
        float w10 = wy * (1.f - wx) * fy1 * fx0;
        float w11 = wy * wx * fy1 * fx1;
        int cx0 = min(max(ix0, 0), 63), cx1 = min(max(ix1, 0), 63);
        int cy0 = min(max(iy0, 0), 63), cy1 = min(max(iy1, 0), 63);
        // element-pair offsets (u32 units): ((y*64+x)*128 + c8) / 2
        int base00 = ((cy0 * 64 + cx0) * CH + c8) >> 1;
        int base01 = ((cy0 * 64 + cx1) * CH + c8) >> 1;
        int base10 = ((cy1 * 64 + cx0) * CH + c8) >> 1;
        int base11 = ((cy1 * 64 + cx1) * CH + c8) >> 1;
        uint4 u00 = *(const uint4*)(xb + base00);
        uint4 u01 = *(const uint4*)(xb + base01);
        uint4 u10 = *(const uint4*)(xb + base10);
        uint4 u11 = *(const uint4*)(xb + base11);
        u32 outp[4];
        const u32* p00 = (const u32*)&u00;
        const u32* p01 = (const u32*)&u01;
        const u32* p10 = (const u32*)&u10;
        const u32* p11 = (const u32*)&u11;
        #pragma unroll
        for (int q = 0; q < 4; ++q) {
            float lo = w00 * bf_lo(p00[q]);
            lo = fmaf(w01, bf_lo(p01[q]), lo);
            lo = fmaf(w10, bf_lo(p10[q]), lo);
            lo = fmaf(w11, bf_lo(p11[q]), lo);
            float hi = w00 * bf_hi(p00[q]);
            hi = fmaf(w01, bf_hi(p01[q]), hi);
            hi = fmaf(w10, bf_hi(p10[q]), hi);
            hi = fmaf(w11, bf_hi(p11[q]), hi);
            outp[q] = pack_bf16(lo, hi);
        }
        *(uint4*)(ao + k * CH) = *(const uint4*)outp;
    }
}

// ---------------- GEMM: 64(o) x 128(pix) tiles, grid (256, 2) ----------------
__global__ __launch_bounds__(256) void gemm_kernel(const u16* __restrict__ Wb,
                                                   const u16* __restrict__ Apix,
                                                   const float* __restrict__ b_main,
                                                   float* __restrict__ out) {
    __shared__ __align__(16) u16 lA[64 * 32];
    __shared__ __align__(16) u16 lB[128 * 32];
    int tid = threadIdx.x;
    int wave = tid >> 6;
    int lane = tid & 63;
    int wmh = wave & 1;               // o 32-half within the 64-tile
    int wn = wave >> 1;               // pixel 64-half
    int ob = blockIdx.y * 64;         // o tile base
    int pb = blockIdx.x * 128;        // pixel tile base
    int mrow = lane & 15;
    int q8 = (lane >> 4) * 8;

    float4v acc[2][4];
    #pragma unroll
    for (int sm = 0; sm < 2; ++sm)
        #pragma unroll
        for (int sn = 0; sn < 4; ++sn)
            acc[sm][sn] = (float4v){0.f, 0.f, 0.f, 0.f};

    const u16* Ap = Wb + (size_t)ob * KD;
    const u16* Bp = Apix + (size_t)pb * KD;

    // staging coords
    int arow = tid >> 2;              // 0..63
    int acol = (tid & 3) * 8;
    int brow0 = tid >> 1;             // 0..127 (first half)
    int bcol0 = (tid & 1) * 16;       // 2 uint4 per row half? -> use 2 loads of 8

    for (int kk = 0; kk < 36; ++kk) {
        int col0 = kk * 32;
        *(uint4*)&lA[(arow * 32) + acol] = *(const uint4*)(Ap + (size_t)arow * KD + col0 + acol);
        #pragma unroll
        for (int q = 0; q < 2; ++q) {
            int idx = q * 256 + tid;
            int row = idx >> 2;
            int cole = (idx & 3) * 8;
            *(uint4*)&lB[row * 32 + cole] = *(const uint4*)(Bp + (size_t)row * KD + col0 + cole);
        }
        __syncthreads();
        short8 af[2], bfv[4];
        #pragma unroll
        for (int s = 0; s < 2; ++s)
            af[s] = *(const short8*)&lA[(wmh * 32 + s * 16 + mrow) * 32 + q8];
        #pragma unroll
        for (int s = 0; s < 4; ++s)
            bfv[s] = *(const short8*)&lB[(wn * 64 + s * 16 + mrow) * 32 + q8];
        #pragma unroll
        for (int sm = 0; sm < 2; ++sm)
            #pragma unroll
            for (int sn = 0; sn < 4; ++sn)
                acc[sm][sn] = __builtin_amdgcn_mfma_f32_16x16x32_bf16(af[sm], bfv[sn],
                                                                     acc[sm][sn], 0, 0, 0);
        __syncthreads();
    }

    // epilogue: C/D layout col=lane&15 (pixel), row=(lane>>4)*4+r (o)
    #pragma unroll
    for (int sm = 0; sm < 2; ++sm) {
        int o = ob + wmh * 32 + sm * 16 + (lane >> 4) * 4;
        #pragma unroll
        for (int sn = 0; sn < 4; ++sn) {
            int pcol = pb + wn * 64 + sn * 16 + mrow;
            int b = pcol >> 12;
            int rem = pcol & 4095;
            float* op = out + (((size_t)b * OO) << 12) + rem;
            #pragma unroll
            for (int r = 0; r < 4; ++r)
                op[(size_t)(o + r) << 12] = acc[sm][sn][r] + b_main[o + r];
        }
    }
}

extern "C" void kernel_launch(void* const* d_in, const int* in_sizes, int n_in,
                              void* d_out, int out_size, void* d_ws, size_t ws_size,
                              hipStream_t stream) {
    const float* x      = (const float*)d_in[0];
    const float* w_off  = (const float*)d_in[1];
    const float* b_off  = (const float*)d_in[2];
    const float* w_main = (const float*)d_in[3];
    const float* b_main = (const float*)d_in[4];
    float* out = (float*)d_out;

    char* ws = (char*)d_ws;
    __hip_bfloat16* xt = (__hip_bfloat16*)ws;                         // 8 MB
    float* partial = (float*)(ws + 8388608);                          // 3 MB
    u16* Wb   = (u16*)(ws + 8388608 + 3145728);                       // 288 KB
    u16* Apix = (u16*)(ws + 8388608 + 3145728 + 294912);              // 72 MB

    transpose_kernel<<<512, 256, 0, stream>>>(x, xt);
    offset_conv_kernel<<<dim3(128, 4), 256, 0, stream>>>(x, w_off, partial);
    wreorder_kernel<<<576, 256, 0, stream>>>(w_main, Wb);
    im2col_kernel<<<MPIX / IMB, 256, 0, stream>>>(xt, partial, b_off, Apix);
    gemm_kernel<<<dim3(256, 2), 256, 0, stream>>>(Wb, Apix, b_main, out);
}